// Round 8
// baseline (260.303 us; speedup 1.0000x reference)
//
#include <hip/hip_runtime.h>
#include <hip/hip_bf16.h>

typedef unsigned short u16;
typedef __attribute__((ext_vector_type(8))) short v8s;   // 8 x bf16 (4 VGPRs)
typedef __attribute__((ext_vector_type(4))) float v4f;   // MFMA accum
typedef __attribute__((ext_vector_type(4))) unsigned v4u;

#define DEV __device__ __forceinline__

DEV u16 f2bf(float f) {
  union { float f; unsigned u; } v; v.f = f;
  unsigned r = v.u + 0x7fffu + ((v.u >> 16) & 1u);  // RNE
  return (u16)(r >> 16);
}

DEV unsigned pk2bf(float a, float b) {
  float2 t; t.x = a; t.y = b;
  __hip_bfloat162 p = __float22bfloat162_rn(t);   // x -> low 16 bits
  union { __hip_bfloat162 h; unsigned u; } c; c.h = p;
  return c.u;
}

DEV void gload_lds16(const void* g, void* l) {
  __builtin_amdgcn_global_load_lds(
      (const __attribute__((address_space(1))) void*)g,
      (__attribute__((address_space(3))) void*)l, 16, 0, 0);
}

// ---------------- f32 -> bf16 convert (vectorized) ----------------
__global__ __launch_bounds__(256) void cvt_bf16(const float* __restrict__ in,
                                                u16* __restrict__ out, int n4) {
  int i = blockIdx.x * 256 + threadIdx.x;
  if (i >= n4) return;
  float4 v = ((const float4*)in)[i];
  ushort4 o;
  o.x = f2bf(v.x); o.y = f2bf(v.y); o.z = f2bf(v.z); o.w = f2bf(v.w);
  ((ushort4*)out)[i] = o;
}

// ---------------- lambda gates (stores 0.125 * sigmoid, i.e. gate*scale) ----
__global__ __launch_bounds__(256) void lam_kernel(const float* __restrict__ Wl1,
    const float* __restrict__ bl1, const float* __restrict__ Wl2,
    const float* __restrict__ bl2, float* __restrict__ lam) {
  int t = blockIdx.x * 256 + threadIdx.x;  // 0..4095
  float lp = logf((float)t + 1.0f);
  float h1[64];
#pragma unroll
  for (int j = 0; j < 64; ++j) h1[j] = fmaxf(lp * Wl1[j] + bl1[j], 0.0f);
#pragma unroll 1
  for (int h = 0; h < 16; ++h) {
    float z = bl2[h];
#pragma unroll
    for (int j = 0; j < 64; ++j) z += h1[j] * Wl2[h * 64 + j];
    lam[h * 4096 + t] = 0.125f / (1.0f + expf(-z));
  }
}

// ---------------- 256x256 bf16 GEMM, 2 phases per K-tile, 1 barrier/phase ----
// (unchanged from round 7: 902 TF, MfmaUtil 40%. Frozen this round.)
template <int MH>
DEV void mfma32(v4f (&acc)[8][4], const v8s (&a)[4][2], const v8s (&b)[4][2]) {
#pragma unroll
  for (int kk = 0; kk < 2; ++kk)
#pragma unroll
    for (int i = 0; i < 4; ++i)
#pragma unroll
      for (int j = 0; j < 4; ++j)
        acc[MH * 4 + i][j] = __builtin_amdgcn_mfma_f32_16x16x32_bf16(
            a[i][kk], b[j][kk], acc[MH * 4 + i][j], 0, 0, 0);
}

DEV void ldA(v8s (&a)[4][2], const u16* Ab, int wr, int mh, int lane) {
  const int l15 = lane & 15, g = lane >> 4;
#pragma unroll
  for (int i = 0; i < 4; ++i) {
    const int row = wr * 128 + mh * 64 + i * 16 + l15;
#pragma unroll
    for (int kk = 0; kk < 2; ++kk)
      a[i][kk] = *(const v8s*)(Ab + row * 64 + (((kk * 4 + g) ^ (row & 7)) << 3));
  }
}

DEV void ldB4(v8s (&b)[4][2], const u16* Bb, int wc, int lane) {
  const int l15 = lane & 15, g = lane >> 4;
#pragma unroll
  for (int j = 0; j < 4; ++j) {
    const int row = (j >> 1) * 128 + wc * 32 + (j & 1) * 16 + l15;
#pragma unroll
    for (int kk = 0; kk < 2; ++kk)
      b[j][kk] = *(const v8s*)(Bb + row * 64 + (((kk * 4 + g) ^ (row & 7)) << 3));
  }
}

template <int OUTF32>
__global__ __launch_bounds__(512, 2) void gemm256(const u16* __restrict__ A,
    const u16* __restrict__ Bt, void* __restrict__ Cout,
    const float* __restrict__ bias, int M, int N, int K) {
  __shared__ u16 As[2][256 * 64];
  __shared__ u16 Bs[2][256 * 64];
  const int tid = threadIdx.x;
  const int lane = tid & 63;
  const int nbn = N >> 8;
  const int nwg = gridDim.x;
  int wg = blockIdx.x;
  wg = (wg & 7) * (nwg >> 3) + (wg >> 3);   // XCD swizzle (nwg % 8 == 0)
  const int m0 = (wg / nbn) << 8;
  const int n0 = (wg % nbn) << 8;
  const int wid = tid >> 6;
  const int wr = wid >> 2;   // 0..1
  const int wc = wid & 3;    // 0..3
  const int nkt = K >> 6;
  const int nit = nkt >> 1;

  auto SAu = [&](int buf, int kt, int u) {
    const int ur = tid >> 3;
    const int slot = (tid & 7) ^ (ur & 7);
    gload_lds16(A + (size_t)(m0 + u * 64 + ur) * K + kt * 64 + slot * 8,
                &As[buf][u * 4096 + (tid & ~63) * 8]);
  };
  auto SBu = [&](int buf, int kt, int u) {
    const int q = tid >> 3;
    const int grow = (((u & 1) * 2 + (q >> 5)) << 6) + ((u >> 1) << 5) + (q & 31);
    const int slot = (tid & 7) ^ (q & 7);
    gload_lds16(Bt + (size_t)(n0 + grow) * K + kt * 64 + slot * 8,
                &Bs[buf][u * 4096 + (tid & ~63) * 8]);
  };
  auto SA_ = [&](int buf, int kt, int mh) { SAu(buf, kt, mh); SAu(buf, kt, 2 + mh); };
  auto SB_ = [&](int buf, int kt, int nh) { SBu(buf, kt, nh * 2); SBu(buf, kt, nh * 2 + 1); };

  v4f acc[8][4] = {};
  v8s a[4][2], b[4][2];

  SA_(0, 0, 0); SA_(0, 0, 1); SB_(0, 0, 0); SB_(0, 0, 1);
  SA_(1, 1, 0); SB_(1, 1, 0); SB_(1, 1, 1);
  asm volatile("s_waitcnt vmcnt(6)" ::: "memory");
  asm volatile("s_barrier" ::: "memory");

#define PHASE(MHc, VM, ...)                                 \
  do { __VA_ARGS__; } while (0);                            \
  __builtin_amdgcn_s_setprio(1);                            \
  mfma32<MHc>(acc, a, b);                                   \
  __builtin_amdgcn_s_setprio(0);                            \
  if (VM) asm volatile("s_waitcnt vmcnt(6)" ::: "memory");  \
  asm volatile("s_barrier" ::: "memory");

  for (int it = 0; it < nit; ++it) {
    const int t0 = 2 * it;
    const int t1 = t0 + 1;
    const int t2 = (t0 + 2 < nkt) ? t0 + 2 : nkt - 1;
    const int t3 = (t0 + 3 < nkt) ? t0 + 3 : nkt - 1;
    ldA(a, As[0], wr, 0, lane); ldB4(b, Bs[0], wc, lane);
    PHASE(0, 0, SAu(1, t1, 1); SAu(1, t1, 3));
    ldA(a, As[0], wr, 1, lane);
    PHASE(1, 1, SB_(0, t2, 0); SB_(0, t2, 1); SAu(0, t2, 0); SAu(0, t2, 2));
    ldA(a, As[1], wr, 0, lane); ldB4(b, Bs[1], wc, lane);
    PHASE(0, 0, SAu(0, t2, 1); SAu(0, t2, 3));
    ldA(a, As[1], wr, 1, lane);
    PHASE(1, 1, SB_(1, t3, 0); SB_(1, t3, 1); SAu(1, t3, 0); SAu(1, t3, 2));
  }
#undef PHASE

  const int l15 = lane & 15, g4 = (lane >> 4) * 4;
#pragma unroll
  for (int i = 0; i < 8; ++i) {
#pragma unroll
    for (int j = 0; j < 4; ++j) {
      const int gr = m0 + wr * 128 + i * 16 + g4;
      const int gc = n0 + wc * 64 + j * 16 + l15;
      float bv = OUTF32 ? bias[gc] : 0.0f;
#pragma unroll
      for (int r = 0; r < 4; ++r) {
        float val = acc[i][j][r];
        if (OUTF32) ((float*)Cout)[(size_t)(gr + r) * N + gc] = val + bv;
        else ((u16*)Cout)[(size_t)(gr + r) * N + gc] = f2bf(val);
      }
    }
  }
}

// ---------------- chunked gated attention, 1024-thread blocks --------------
// One block per (b, h, chunk), 16 waves (4 waves/SIMD: doubles occupancy vs
// 512-thread version — waves are barrier-free after staging, so more waves
// per SIMD directly hides ds_read latency + exp-chain serialization).
// Swapped QK^T; lane owns ONE q; keys in 4 online quarters of 128.
__global__ __launch_bounds__(1024, 4) void attn_chunk(const u16* __restrict__ qkv,
    const float* __restrict__ lam, u16* __restrict__ aout) {
  __shared__ u16 Ksm[512 * 64];   // [key][dim], slot ^= f(row), f = bits{0,1,3}
  __shared__ u16 Vt[64 * 520];    // [dim][key], +8 pad per row
  __shared__ float lam_s[512];

  const int tid = threadIdx.x;
  const int lane = tid & 63;
  const int wid = tid >> 6;            // 0..15
  const int blk = blockIdx.x;          // b*128 + h*8 + c
  const int c = blk & 7;
  const int h = (blk >> 3) & 15;
  const int b = blk >> 7;
  const size_t tok0 = (size_t)b * 4096 + c * 512;
  const u16* qb = qkv + tok0 * 3072 + h * 64;
  const u16* kb = qb + 1024;
  const u16* vb = qb + 2048;

  if (tid < 512) lam_s[tid] = lam[h * 4096 + c * 512 + tid];  // incl. 0.125

  // stage K: linear LDS dest, source col pre-swizzled by f(row). 16 waves x
  // 8 rows x 4 iters = 512 rows.
#pragma unroll
  for (int i = 0; i < 4; ++i) {
    const int r = i * 128 + wid * 8 + (lane >> 3);
    const int f = (r & 3) | (((r >> 3) & 1) << 2);
    gload_lds16(kb + (size_t)r * 3072 + (((lane & 7) ^ f) << 3),
                &Ksm[(i * 128 + wid * 8) * 64]);
  }
  // stage V transposed (reg-staged, pack 2 keys per 4B write); 1024 threads:
  // (pr, quarter) -> 2 dim-blocks each.
  {
    const int pr = tid & 255;            // key pair 2pr, 2pr+1
    const int db0 = (tid >> 8) * 2;      // dim-block pair
#pragma unroll
    for (int dbi = 0; dbi < 2; ++dbi) {
      const int d0 = (db0 + dbi) * 8;
      v8s v0 = *(const v8s*)(vb + (size_t)(2 * pr) * 3072 + d0);
      v8s v1 = *(const v8s*)(vb + (size_t)(2 * pr + 1) * 3072 + d0);
#pragma unroll
      for (int j = 0; j < 8; ++j) {
        unsigned pk = (unsigned)(u16)v0[j] | ((unsigned)(u16)v1[j] << 16);
        *(unsigned*)&Vt[(d0 + j) * 520 + 2 * pr] = pk;
      }
    }
  }
  __syncthreads();

  const int l15 = lane & 15;
  const int gg = lane >> 4;
  // kf row permutation: tile (kp,hh) row m -> key kp*32 + (m>>2)*8 + hh*4 + (m&3)
  const int rbase = ((l15 >> 2) << 3) + (l15 & 3);
  const int fsl = (l15 & 3) | (((l15 >> 2) & 1) << 2);
  const int sl0 = ((gg ^ fsl) << 3);
  const int sl1 = (((4 + gg) ^ fsl) << 3);

#pragma unroll 1
  for (int pass = 0; pass < 2; ++pass) {
    const int q0 = pass * 256 + wid * 16;
    const v8s qf0 = *(const v8s*)(qb + (size_t)(q0 + l15) * 3072 + gg * 8);
    const v8s qf1 = *(const v8s*)(qb + (size_t)(q0 + l15) * 3072 + 32 + gg * 8);

    float m = -1e30f, sum = 0.0f;
    v4f o[4] = {};

#pragma unroll 1
    for (int qtr = 0; qtr < 4; ++qtr) {
      // S^T quarter: keys qtr*128 + kpl*32 + gg*8 + hh*4 + r, gated in f32
      v4f s[8];
#pragma unroll
      for (int kpl = 0; kpl < 4; ++kpl) {
#pragma unroll
        for (int hh = 0; hh < 2; ++hh) {
          const int rw = (qtr * 128 + kpl * 32 + rbase + hh * 4) << 6;
          v4f z = {0.f, 0.f, 0.f, 0.f};
          z = __builtin_amdgcn_mfma_f32_16x16x32_bf16(
              *(const v8s*)&Ksm[rw + sl0], qf0, z, 0, 0, 0);
          z = __builtin_amdgcn_mfma_f32_16x16x32_bf16(
              *(const v8s*)&Ksm[rw + sl1], qf1, z, 0, 0, 0);
          const v4f lv = *(const v4f*)&lam_s[qtr * 128 + kpl * 32 + gg * 8 + hh * 4];
          s[kpl * 2 + hh] = z * lv;
        }
      }
      // online softmax update (row = 4 lanes sharing q: xor16, xor32)
      v4f vm = s[0];
#pragma unroll
      for (int kt = 1; kt < 8; ++kt)
#pragma unroll
        for (int r = 0; r < 4; ++r) vm[r] = fmaxf(vm[r], s[kt][r]);
      float qmax = fmaxf(fmaxf(vm[0], vm[1]), fmaxf(vm[2], vm[3]));
      qmax = fmaxf(qmax, __shfl_xor(qmax, 16));
      qmax = fmaxf(qmax, __shfl_xor(qmax, 32));
      const float newm = fmaxf(m, qmax);
      const float scale = __expf(m - newm);
      m = newm;
      float psum = 0.f;
#pragma unroll
      for (int kt = 0; kt < 8; ++kt)
#pragma unroll
        for (int r = 0; r < 4; ++r) {
          s[kt][r] = __expf(s[kt][r] - m);
          psum += s[kt][r];
        }
      sum = sum * scale + psum;
#pragma unroll
      for (int dt = 0; dt < 4; ++dt)
#pragma unroll
        for (int r = 0; r < 4; ++r) o[dt][r] *= scale;

      // PV quarter: P^T B-frag built in-register (regs already in order)
#pragma unroll
      for (int kpl = 0; kpl < 4; ++kpl) {
        v4u pwv;
        pwv.x = pk2bf(s[2 * kpl][0], s[2 * kpl][1]);
        pwv.y = pk2bf(s[2 * kpl][2], s[2 * kpl][3]);
        pwv.z = pk2bf(s[2 * kpl + 1][0], s[2 * kpl + 1][1]);
        pwv.w = pk2bf(s[2 * kpl + 1][2], s[2 * kpl + 1][3]);
        const v8s pf = __builtin_bit_cast(v8s, pwv);
#pragma unroll
        for (int dt = 0; dt < 4; ++dt) {
          const v8s vf = *(const v8s*)&Vt[(dt * 16 + l15) * 520 +
                                          (qtr * 4 + kpl) * 32 + gg * 8];
          o[dt] = __builtin_amdgcn_mfma_f32_16x16x32_bf16(vf, pf, o[dt], 0, 0, 0);
        }
      }
    }

    sum += __shfl_xor(sum, 16);
    sum += __shfl_xor(sum, 32);
    const float sminv = 1.0f / sum;

    // write O^T: lane's col = q (l15); rows = d = dt*16 + gg*4 + r
    const size_t obase = (tok0 + q0 + l15) * 1024 + h * 64;
#pragma unroll
    for (int dt = 0; dt < 4; ++dt) {
      ushort4 w;
      w.x = f2bf(o[dt][0] * sminv); w.y = f2bf(o[dt][1] * sminv);
      w.z = f2bf(o[dt][2] * sminv); w.w = f2bf(o[dt][3] * sminv);
      *(ushort4*)&aout[obase + dt * 16 + gg * 4] = w;
    }
  }
}

extern "C" void kernel_launch(void* const* d_in, const int* in_sizes, int n_in,
                              void* d_out, int out_size, void* d_ws, size_t ws_size,
                              hipStream_t stream) {
  const float* x    = (const float*)d_in[0];
  const float* Wqkv = (const float*)d_in[1];
  const float* Wout = (const float*)d_in[2];
  const float* bout = (const float*)d_in[3];
  const float* Wl1  = (const float*)d_in[4];
  const float* bl1  = (const float*)d_in[5];
  const float* Wl2  = (const float*)d_in[6];
  const float* bl2  = (const float*)d_in[7];
  float* out = (float*)d_out;

  char* ws = (char*)d_ws;
  u16* xbf    = (u16*)ws; ws += (size_t)16384 * 1024 * 2;
  u16* wqkvbf = (u16*)ws; ws += (size_t)3072 * 1024 * 2;
  u16* woutbf = (u16*)ws; ws += (size_t)1024 * 1024 * 2;
  u16* qkvbf  = (u16*)ws; ws += (size_t)16384 * 3072 * 2;
  u16* aoutbf = (u16*)ws; ws += (size_t)16384 * 1024 * 2;
  float* lam  = (float*)ws; ws += (size_t)16 * 4096 * 4;

  cvt_bf16<<<16384, 256, 0, stream>>>(x, xbf, 16777216 / 4);
  cvt_bf16<<<3072, 256, 0, stream>>>(Wqkv, wqkvbf, 3145728 / 4);
  cvt_bf16<<<1024, 256, 0, stream>>>(Wout, woutbf, 1048576 / 4);
  lam_kernel<<<16, 256, 0, stream>>>(Wl1, bl1, Wl2, bl2, lam);

  // QKV projection: 16384x3072x1024, 768 blocks
  gemm256<0><<<dim3((16384 / 256) * (3072 / 256)), 512, 0, stream>>>(
      xbf, wqkvbf, qkvbf, nullptr, 16384, 3072, 1024);

  attn_chunk<<<512, 1024, 0, stream>>>(qkvbf, lam, aoutbf);

  // output projection: 16384x1024x1024, 256 blocks
  gemm256<1><<<dim3((16384 / 256) * (1024 / 256)), 512, 0, stream>>>(
      aoutbf, woutbf, out, bout, 16384, 1024, 1024);
}

// Round 9
// 248.418 us; speedup vs baseline: 1.0478x; 1.0478x over previous
//
#include <hip/hip_runtime.h>
#include <hip/hip_bf16.h>

typedef unsigned short u16;
typedef __attribute__((ext_vector_type(8))) short v8s;    // 8 x bf16 (4 VGPRs)
typedef __attribute__((ext_vector_type(4))) float v4f;    // MFMA accum 16x16
typedef __attribute__((ext_vector_type(16))) float v16f;  // MFMA accum 32x32
typedef __attribute__((ext_vector_type(4))) unsigned v4u;

#define DEV __device__ __forceinline__

DEV u16 f2bf(float f) {
  union { float f; unsigned u; } v; v.f = f;
  unsigned r = v.u + 0x7fffu + ((v.u >> 16) & 1u);  // RNE
  return (u16)(r >> 16);
}

DEV unsigned pk2bf(float a, float b) {
  float2 t; t.x = a; t.y = b;
  __hip_bfloat162 p = __float22bfloat162_rn(t);   // x -> low 16 bits
  union { __hip_bfloat162 h; unsigned u; } c; c.h = p;
  return c.u;
}

DEV void gload_lds16(const void* g, void* l) {
  __builtin_amdgcn_global_load_lds(
      (const __attribute__((address_space(1))) void*)g,
      (__attribute__((address_space(3))) void*)l, 16, 0, 0);
}

// ---------------- f32 -> bf16 convert (vectorized) ----------------
__global__ __launch_bounds__(256) void cvt_bf16(const float* __restrict__ in,
                                                u16* __restrict__ out, int n4) {
  int i = blockIdx.x * 256 + threadIdx.x;
  if (i >= n4) return;
  float4 v = ((const float4*)in)[i];
  ushort4 o;
  o.x = f2bf(v.x); o.y = f2bf(v.y); o.z = f2bf(v.z); o.w = f2bf(v.w);
  ((ushort4*)out)[i] = o;
}

// ---------------- lambda gates (stores 0.125 * sigmoid) ----------------
__global__ __launch_bounds__(256) void lam_kernel(const float* __restrict__ Wl1,
    const float* __restrict__ bl1, const float* __restrict__ Wl2,
    const float* __restrict__ bl2, float* __restrict__ lam) {
  int t = blockIdx.x * 256 + threadIdx.x;  // 0..4095
  float lp = logf((float)t + 1.0f);
  float h1[64];
#pragma unroll
  for (int j = 0; j < 64; ++j) h1[j] = fmaxf(lp * Wl1[j] + bl1[j], 0.0f);
#pragma unroll 1
  for (int h = 0; h < 16; ++h) {
    float z = bl2[h];
#pragma unroll
    for (int j = 0; j < 64; ++j) z += h1[j] * Wl2[h * 64 + j];
    lam[h * 4096 + t] = 0.125f / (1.0f + expf(-z));
  }
}

// ---------------- 256x256 bf16 GEMM (frozen: 902 TF, round-7 form) ----------
template <int MH>
DEV void mfma32(v4f (&acc)[8][4], const v8s (&a)[4][2], const v8s (&b)[4][2]) {
#pragma unroll
  for (int kk = 0; kk < 2; ++kk)
#pragma unroll
    for (int i = 0; i < 4; ++i)
#pragma unroll
      for (int j = 0; j < 4; ++j)
        acc[MH * 4 + i][j] = __builtin_amdgcn_mfma_f32_16x16x32_bf16(
            a[i][kk], b[j][kk], acc[MH * 4 + i][j], 0, 0, 0);
}

DEV void ldA(v8s (&a)[4][2], const u16* Ab, int wr, int mh, int lane) {
  const int l15 = lane & 15, g = lane >> 4;
#pragma unroll
  for (int i = 0; i < 4; ++i) {
    const int row = wr * 128 + mh * 64 + i * 16 + l15;
#pragma unroll
    for (int kk = 0; kk < 2; ++kk)
      a[i][kk] = *(const v8s*)(Ab + row * 64 + (((kk * 4 + g) ^ (row & 7)) << 3));
  }
}

DEV void ldB4(v8s (&b)[4][2], const u16* Bb, int wc, int lane) {
  const int l15 = lane & 15, g = lane >> 4;
#pragma unroll
  for (int j = 0; j < 4; ++j) {
    const int row = (j >> 1) * 128 + wc * 32 + (j & 1) * 16 + l15;
#pragma unroll
    for (int kk = 0; kk < 2; ++kk)
      b[j][kk] = *(const v8s*)(Bb + row * 64 + (((kk * 4 + g) ^ (row & 7)) << 3));
  }
}

template <int OUTF32>
__global__ __launch_bounds__(512, 2) void gemm256(const u16* __restrict__ A,
    const u16* __restrict__ Bt, void* __restrict__ Cout,
    const float* __restrict__ bias, int M, int N, int K) {
  __shared__ u16 As[2][256 * 64];
  __shared__ u16 Bs[2][256 * 64];
  const int tid = threadIdx.x;
  const int lane = tid & 63;
  const int nbn = N >> 8;
  const int nwg = gridDim.x;
  int wg = blockIdx.x;
  wg = (wg & 7) * (nwg >> 3) + (wg >> 3);   // XCD swizzle (nwg % 8 == 0)
  const int m0 = (wg / nbn) << 8;
  const int n0 = (wg % nbn) << 8;
  const int wid = tid >> 6;
  const int wr = wid >> 2;   // 0..1
  const int wc = wid & 3;    // 0..3
  const int nkt = K >> 6;
  const int nit = nkt >> 1;

  auto SAu = [&](int buf, int kt, int u) {
    const int ur = tid >> 3;
    const int slot = (tid & 7) ^ (ur & 7);
    gload_lds16(A + (size_t)(m0 + u * 64 + ur) * K + kt * 64 + slot * 8,
                &As[buf][u * 4096 + (tid & ~63) * 8]);
  };
  auto SBu = [&](int buf, int kt, int u) {
    const int q = tid >> 3;
    const int grow = (((u & 1) * 2 + (q >> 5)) << 6) + ((u >> 1) << 5) + (q & 31);
    const int slot = (tid & 7) ^ (q & 7);
    gload_lds16(Bt + (size_t)(n0 + grow) * K + kt * 64 + slot * 8,
                &Bs[buf][u * 4096 + (tid & ~63) * 8]);
  };
  auto SA_ = [&](int buf, int kt, int mh) { SAu(buf, kt, mh); SAu(buf, kt, 2 + mh); };
  auto SB_ = [&](int buf, int kt, int nh) { SBu(buf, kt, nh * 2); SBu(buf, kt, nh * 2 + 1); };

  v4f acc[8][4] = {};
  v8s a[4][2], b[4][2];

  SA_(0, 0, 0); SA_(0, 0, 1); SB_(0, 0, 0); SB_(0, 0, 1);
  SA_(1, 1, 0); SB_(1, 1, 0); SB_(1, 1, 1);
  asm volatile("s_waitcnt vmcnt(6)" ::: "memory");
  asm volatile("s_barrier" ::: "memory");

#define PHASE(MHc, VM, ...)                                 \
  do { __VA_ARGS__; } while (0);                            \
  __builtin_amdgcn_s_setprio(1);                            \
  mfma32<MHc>(acc, a, b);                                   \
  __builtin_amdgcn_s_setprio(0);                            \
  if (VM) asm volatile("s_waitcnt vmcnt(6)" ::: "memory");  \
  asm volatile("s_barrier" ::: "memory");

  for (int it = 0; it < nit; ++it) {
    const int t0 = 2 * it;
    const int t1 = t0 + 1;
    const int t2 = (t0 + 2 < nkt) ? t0 + 2 : nkt - 1;
    const int t3 = (t0 + 3 < nkt) ? t0 + 3 : nkt - 1;
    ldA(a, As[0], wr, 0, lane); ldB4(b, Bs[0], wc, lane);
    PHASE(0, 0, SAu(1, t1, 1); SAu(1, t1, 3));
    ldA(a, As[0], wr, 1, lane);
    PHASE(1, 1, SB_(0, t2, 0); SB_(0, t2, 1); SAu(0, t2, 0); SAu(0, t2, 2));
    ldA(a, As[1], wr, 0, lane); ldB4(b, Bs[1], wc, lane);
    PHASE(0, 0, SAu(0, t2, 1); SAu(0, t2, 3));
    ldA(a, As[1], wr, 1, lane);
    PHASE(1, 1, SB_(1, t3, 0); SB_(1, t3, 1); SAu(1, t3, 0); SAu(1, t3, 2));
  }
#undef PHASE

  const int l15 = lane & 15, g4 = (lane >> 4) * 4;
#pragma unroll
  for (int i = 0; i < 8; ++i) {
#pragma unroll
    for (int j = 0; j < 4; ++j) {
      const int gr = m0 + wr * 128 + i * 16 + g4;
      const int gc = n0 + wc * 64 + j * 16 + l15;
      float bv = OUTF32 ? bias[gc] : 0.0f;
#pragma unroll
      for (int r = 0; r < 4; ++r) {
        float val = acc[i][j][r];
        if (OUTF32) ((float*)Cout)[(size_t)(gr + r) * N + gc] = val + bv;
        else ((u16*)Cout)[(size_t)(gr + r) * N + gc] = f2bf(val);
      }
    }
  }
}

// ---------------- chunked gated attention, 32x32 MFMA ----------------------
// One block per (b,h,chunk), 8 waves x 32 q x 2 passes. Swapped QK^T with
// mfma_32x32x16: C col = lane&31 = q (lane-local softmax; partner lane^32
// holds the other 16 keys of the SAME q). V staged transposed with key
// columns PERMUTED (sigma) so each lane's C-regs are exactly its PV B-frag
// in order -> zero cross-lane traffic for P. Online softmax per 32-key tile
// with defer-max (T13, THR=8). Halves LDS reads + MFMA instr count vs 16x16.
__global__ __launch_bounds__(512) void attn_chunk(const u16* __restrict__ qkv,
    const float* __restrict__ lam, u16* __restrict__ aout) {
  __shared__ u16 Ksm[512 * 64];   // [key][dim], slot ^= f(row), f = bits{0,1,3}
  __shared__ u16 Vt[64 * 520];    // [dim][perm(key)], +8 pad per row
  __shared__ float lam_s[512];

  const int tid = threadIdx.x;
  const int lane = tid & 63;
  const int wid = tid >> 6;            // 0..7
  const int blk = blockIdx.x;          // b*128 + h*8 + c
  const int c = blk & 7;
  const int hd = (blk >> 3) & 15;
  const int b = blk >> 7;
  const size_t tok0 = (size_t)b * 4096 + c * 512;
  const u16* qb = qkv + tok0 * 3072 + hd * 64;
  const u16* kb = qb + 1024;
  const u16* vb = qb + 2048;

  lam_s[tid] = lam[hd * 4096 + c * 512 + tid];   // includes 0.125 scale

  // stage K: linear LDS dest, source col pre-swizzled by f(row)
#pragma unroll
  for (int i = 0; i < 8; ++i) {
    const int r = i * 64 + wid * 8 + (lane >> 3);
    const int f = (r & 3) | (((r >> 3) & 1) << 2);
    gload_lds16(kb + (size_t)r * 3072 + (((lane & 7) ^ f) << 3),
                &Ksm[(i * 64 + wid * 8) * 64]);
  }
  // stage V transposed + column-permuted: key k -> col (k&~31) + (kg&16)
  //   + ((kg>>2)&1)*8 + ((kg&3)|((kg&8)>>1)); pairs (2i,2i+1) stay adjacent.
  {
    const int pr = tid & 255;
    const int k0 = 2 * pr;
    const int kg = k0 & 31;
    const int col = (k0 & ~31) + (kg & 16) + (((kg >> 2) & 1) << 3) +
                    ((kg & 3) | ((kg & 8) >> 1));
    const int db0 = (tid >> 8) * 4;
#pragma unroll
    for (int dbi = 0; dbi < 4; ++dbi) {
      const int d0 = (db0 + dbi) * 8;
      v8s v0 = *(const v8s*)(vb + (size_t)k0 * 3072 + d0);
      v8s v1 = *(const v8s*)(vb + (size_t)(k0 + 1) * 3072 + d0);
#pragma unroll
      for (int j = 0; j < 8; ++j) {
        unsigned pk = (unsigned)(u16)v0[j] | ((unsigned)(u16)v1[j] << 16);
        *(unsigned*)&Vt[(d0 + j) * 520 + col] = pk;
      }
    }
  }
  __syncthreads();

  const int l31 = lane & 31;
  const int hf = lane >> 5;                               // key/dim half
  const int fk = (l31 & 3) | (((l31 >> 3) & 1) << 2);     // f(key row), lane-const

#pragma unroll 1
  for (int pass = 0; pass < 2; ++pass) {
    const int q0 = pass * 256 + wid * 32;
    v8s qv[4];
#pragma unroll
    for (int dsec = 0; dsec < 4; ++dsec)
      qv[dsec] = *(const v8s*)(qb + (size_t)(q0 + l31) * 3072 + dsec * 16 + hf * 8);

    float m = -1e30f, sum = 0.0f;
    v16f o0 = {}, o1 = {};

#pragma unroll 1
    for (int kt = 0; kt < 16; ++kt) {
      // S^T tile: 32 keys x 32 q; lane holds q=q0+l31, 16 keys
      v16f acc = {};
#pragma unroll
      for (int dsec = 0; dsec < 4; ++dsec) {
        const v8s kf = *(const v8s*)&Ksm[(kt * 32 + l31) * 64 +
                                         (((dsec * 2 + hf) ^ fk) << 3)];
        acc = __builtin_amdgcn_mfma_f32_32x32x16_bf16(kf, qv[dsec], acc, 0, 0, 0);
      }
      // gate: C reg r -> key kt*32 + (r&3) + 8*(r>>2) + 4*hf
#pragma unroll
      for (int a = 0; a < 4; ++a) {
        const v4f lv = *(const v4f*)&lam_s[kt * 32 + a * 8 + hf * 4];
#pragma unroll
        for (int i = 0; i < 4; ++i) acc[4 * a + i] *= lv[i];
      }
      // defer-max online softmax (T13, THR=8)
      float tm = acc[0];
#pragma unroll
      for (int r = 1; r < 16; ++r) tm = fmaxf(tm, acc[r]);
      tm = fmaxf(tm, __shfl_xor(tm, 32));
      if (!__all(tm <= m + 8.0f)) {
        const float nm = fmaxf(m, tm);
        const float sc = __expf(m - nm);
        sum *= sc;
        o0 *= sc; o1 *= sc;
        m = nm;
      }
      float ps = 0.0f;
#pragma unroll
      for (int r = 0; r < 16; ++r) { acc[r] = __expf(acc[r] - m); ps += acc[r]; }
      sum += ps;
      // PV: B-frags are the lane's own regs in order (sigma-permuted V cols)
      v4u pa, pb;
      pa.x = pk2bf(acc[0], acc[1]);   pa.y = pk2bf(acc[2], acc[3]);
      pa.z = pk2bf(acc[4], acc[5]);   pa.w = pk2bf(acc[6], acc[7]);
      pb.x = pk2bf(acc[8], acc[9]);   pb.y = pk2bf(acc[10], acc[11]);
      pb.z = pk2bf(acc[12], acc[13]); pb.w = pk2bf(acc[14], acc[15]);
      const v8s pfA = __builtin_bit_cast(v8s, pa);
      const v8s pfB = __builtin_bit_cast(v8s, pb);
      const int vcol = kt * 32 + hf * 8;
      const v8s vA0 = *(const v8s*)&Vt[l31 * 520 + vcol];
      const v8s vB0 = *(const v8s*)&Vt[l31 * 520 + vcol + 16];
      const v8s vA1 = *(const v8s*)&Vt[(32 + l31) * 520 + vcol];
      const v8s vB1 = *(const v8s*)&Vt[(32 + l31) * 520 + vcol + 16];
      o0 = __builtin_amdgcn_mfma_f32_32x32x16_bf16(vA0, pfA, o0, 0, 0, 0);
      o0 = __builtin_amdgcn_mfma_f32_32x32x16_bf16(vB0, pfB, o0, 0, 0, 0);
      o1 = __builtin_amdgcn_mfma_f32_32x32x16_bf16(vA1, pfA, o1, 0, 0, 0);
      o1 = __builtin_amdgcn_mfma_f32_32x32x16_bf16(vB1, pfB, o1, 0, 0, 0);
    }

    sum += __shfl_xor(sum, 32);
    const float sv = 1.0f / sum;

    // write O^T: lane's q = l31; dim = dt*32 + 8*a + 4*hf + i
    const size_t obase = (tok0 + q0 + l31) * 1024 + hd * 64;
#pragma unroll
    for (int a = 0; a < 4; ++a) {
      ushort4 w0, w1;
      w0.x = f2bf(o0[4 * a + 0] * sv); w0.y = f2bf(o0[4 * a + 1] * sv);
      w0.z = f2bf(o0[4 * a + 2] * sv); w0.w = f2bf(o0[4 * a + 3] * sv);
      w1.x = f2bf(o1[4 * a + 0] * sv); w1.y = f2bf(o1[4 * a + 1] * sv);
      w1.z = f2bf(o1[4 * a + 2] * sv); w1.w = f2bf(o1[4 * a + 3] * sv);
      *(ushort4*)&aout[obase + 8 * a + 4 * hf] = w0;
      *(ushort4*)&aout[obase + 32 + 8 * a + 4 * hf] = w1;
    }
  }
}

extern "C" void kernel_launch(void* const* d_in, const int* in_sizes, int n_in,
                              void* d_out, int out_size, void* d_ws, size_t ws_size,
                              hipStream_t stream) {
  const float* x    = (const float*)d_in[0];
  const float* Wqkv = (const float*)d_in[1];
  const float* Wout = (const float*)d_in[2];
  const float* bout = (const float*)d_in[3];
  const float* Wl1  = (const float*)d_in[4];
  const float* bl1  = (const float*)d_in[5];
  const float* Wl2  = (const float*)d_in[6];
  const float* bl2  = (const float*)d_in[7];
  float* out = (float*)d_out;

  char* ws = (char*)d_ws;
  u16* xbf    = (u16*)ws; ws += (size_t)16384 * 1024 * 2;
  u16* wqkvbf = (u16*)ws; ws += (size_t)3072 * 1024 * 2;
  u16* woutbf = (u16*)ws; ws += (size_t)1024 * 1024 * 2;
  u16* qkvbf  = (u16*)ws; ws += (size_t)16384 * 3072 * 2;
  u16* aoutbf = (u16*)ws; ws += (size_t)16384 * 1024 * 2;
  float* lam  = (float*)ws; ws += (size_t)16 * 4096 * 4;

  cvt_bf16<<<16384, 256, 0, stream>>>(x, xbf, 16777216 / 4);
  cvt_bf16<<<3072, 256, 0, stream>>>(Wqkv, wqkvbf, 3145728 / 4);
  cvt_bf16<<<1024, 256, 0, stream>>>(Wout, woutbf, 1048576 / 4);
  lam_kernel<<<16, 256, 0, stream>>>(Wl1, bl1, Wl2, bl2, lam);

  // QKV projection: 16384x3072x1024, 768 blocks
  gemm256<0><<<dim3((16384 / 256) * (3072 / 256)), 512, 0, stream>>>(
      xbf, wqkvbf, qkvbf, nullptr, 16384, 3072, 1024);

  attn_chunk<<<512, 512, 0, stream>>>(qkvbf, lam, aoutbf);

  // output projection: 16384x1024x1024, 256 blocks
  gemm256<1><<<dim3((16384 / 256) * (1024 / 256)), 512, 0, stream>>>(
      aoutbf, woutbf, out, bout, 16384, 1024, 1024);
}

// Round 10
// 244.701 us; speedup vs baseline: 1.0638x; 1.0152x over previous
//
#include <hip/hip_runtime.h>
#include <hip/hip_bf16.h>

typedef unsigned short u16;
typedef __attribute__((ext_vector_type(8))) short v8s;    // 8 x bf16 (4 VGPRs)
typedef __attribute__((ext_vector_type(4))) float v4f;    // MFMA accum 16x16
typedef __attribute__((ext_vector_type(16))) float v16f;  // MFMA accum 32x32
typedef __attribute__((ext_vector_type(4))) unsigned v4u;

#define DEV __device__ __forceinline__

DEV u16 f2bf(float f) {
  union { float f; unsigned u; } v; v.f = f;
  unsigned r = v.u + 0x7fffu + ((v.u >> 16) & 1u);  // RNE
  return (u16)(r >> 16);
}

DEV unsigned pk2bf(float a, float b) {
  float2 t; t.x = a; t.y = b;
  __hip_bfloat162 p = __float22bfloat162_rn(t);   // x -> low 16 bits
  union { __hip_bfloat162 h; unsigned u; } c; c.h = p;
  return c.u;
}

DEV void gload_lds16(const void* g, void* l) {
  __builtin_amdgcn_global_load_lds(
      (const __attribute__((address_space(1))) void*)g,
      (__attribute__((address_space(3))) void*)l, 16, 0, 0);
}

// ---------------- f32 -> bf16 convert (vectorized) ----------------
__global__ __launch_bounds__(256) void cvt_bf16(const float* __restrict__ in,
                                                u16* __restrict__ out, int n4) {
  int i = blockIdx.x * 256 + threadIdx.x;
  if (i >= n4) return;
  float4 v = ((const float4*)in)[i];
  ushort4 o;
  o.x = f2bf(v.x); o.y = f2bf(v.y); o.z = f2bf(v.z); o.w = f2bf(v.w);
  ((ushort4*)out)[i] = o;
}

// ---------------- lambda gates (stores 0.125 * sigmoid) ----------------
__global__ __launch_bounds__(256) void lam_kernel(const float* __restrict__ Wl1,
    const float* __restrict__ bl1, const float* __restrict__ Wl2,
    const float* __restrict__ bl2, float* __restrict__ lam) {
  int t = blockIdx.x * 256 + threadIdx.x;  // 0..4095
  float lp = logf((float)t + 1.0f);
  float h1[64];
#pragma unroll
  for (int j = 0; j < 64; ++j) h1[j] = fmaxf(lp * Wl1[j] + bl1[j], 0.0f);
#pragma unroll 1
  for (int h = 0; h < 16; ++h) {
    float z = bl2[h];
#pragma unroll
    for (int j = 0; j < 64; ++j) z += h1[j] * Wl2[h * 64 + j];
    lam[h * 4096 + t] = 0.125f / (1.0f + expf(-z));
  }
}

// ---------------- 256x256 bf16 GEMM, 2 phases/K-tile, A-frag prefetch -------
// P1/P3 issue ALL ds_reads for the K-tile (a0, b, prefetch a1); P2/P4 are
// pure-MFMA phases (operands already in regs -> no lgkm gate after barrier).
// Hazard audit: P2/P4 stages write only mh0 A-rows + B; the only reads still
// outstanding at the preceding barrier are mh1 A-rows (disjoint); b reads are
// pinned by the preceding MFMA's lgkm wait. vmcnt schedule = round-7 (valid).
template <int MH>
DEV void mfma32(v4f (&acc)[8][4], const v8s (&a)[4][2], const v8s (&b)[4][2]) {
#pragma unroll
  for (int kk = 0; kk < 2; ++kk)
#pragma unroll
    for (int i = 0; i < 4; ++i)
#pragma unroll
      for (int j = 0; j < 4; ++j)
        acc[MH * 4 + i][j] = __builtin_amdgcn_mfma_f32_16x16x32_bf16(
            a[i][kk], b[j][kk], acc[MH * 4 + i][j], 0, 0, 0);
}

DEV void ldA(v8s (&a)[4][2], const u16* Ab, int wr, int mh, int lane) {
  const int l15 = lane & 15, g = lane >> 4;
#pragma unroll
  for (int i = 0; i < 4; ++i) {
    const int row = wr * 128 + mh * 64 + i * 16 + l15;
#pragma unroll
    for (int kk = 0; kk < 2; ++kk)
      a[i][kk] = *(const v8s*)(Ab + row * 64 + (((kk * 4 + g) ^ (row & 7)) << 3));
  }
}

DEV void ldB4(v8s (&b)[4][2], const u16* Bb, int wc, int lane) {
  const int l15 = lane & 15, g = lane >> 4;
#pragma unroll
  for (int j = 0; j < 4; ++j) {
    const int row = (j >> 1) * 128 + wc * 32 + (j & 1) * 16 + l15;
#pragma unroll
    for (int kk = 0; kk < 2; ++kk)
      b[j][kk] = *(const v8s*)(Bb + row * 64 + (((kk * 4 + g) ^ (row & 7)) << 3));
  }
}

template <int OUTF32>
__global__ __launch_bounds__(512, 2) void gemm256(const u16* __restrict__ A,
    const u16* __restrict__ Bt, void* __restrict__ Cout,
    const float* __restrict__ bias, int M, int N, int K) {
  __shared__ u16 As[2][256 * 64];
  __shared__ u16 Bs[2][256 * 64];
  const int tid = threadIdx.x;
  const int lane = tid & 63;
  const int nbn = N >> 8;
  const int nwg = gridDim.x;
  int wg = blockIdx.x;
  wg = (wg & 7) * (nwg >> 3) + (wg >> 3);   // XCD swizzle (nwg % 8 == 0)
  const int m0 = (wg / nbn) << 8;
  const int n0 = (wg % nbn) << 8;
  const int wid = tid >> 6;
  const int wr = wid >> 2;   // 0..1
  const int wc = wid & 3;    // 0..3
  const int nkt = K >> 6;
  const int nit = nkt >> 1;

  auto SAu = [&](int buf, int kt, int u) {
    const int ur = tid >> 3;
    const int slot = (tid & 7) ^ (ur & 7);
    gload_lds16(A + (size_t)(m0 + u * 64 + ur) * K + kt * 64 + slot * 8,
                &As[buf][u * 4096 + (tid & ~63) * 8]);
  };
  auto SBu = [&](int buf, int kt, int u) {
    const int q = tid >> 3;
    const int grow = (((u & 1) * 2 + (q >> 5)) << 6) + ((u >> 1) << 5) + (q & 31);
    const int slot = (tid & 7) ^ (q & 7);
    gload_lds16(Bt + (size_t)(n0 + grow) * K + kt * 64 + slot * 8,
                &Bs[buf][u * 4096 + (tid & ~63) * 8]);
  };
  auto SA_ = [&](int buf, int kt, int mh) { SAu(buf, kt, mh); SAu(buf, kt, 2 + mh); };
  auto SB_ = [&](int buf, int kt, int nh) { SBu(buf, kt, nh * 2); SBu(buf, kt, nh * 2 + 1); };

  v4f acc[8][4] = {};
  v8s a0[4][2], a1[4][2], b[4][2];

  SA_(0, 0, 0); SA_(0, 0, 1); SB_(0, 0, 0); SB_(0, 0, 1);
  SA_(1, 1, 0); SB_(1, 1, 0); SB_(1, 1, 1);
  asm volatile("s_waitcnt vmcnt(6)" ::: "memory");
  asm volatile("s_barrier" ::: "memory");

#define PHASE(MHc, AREG, VM, ...)                           \
  do { __VA_ARGS__; } while (0);                            \
  __builtin_amdgcn_s_setprio(1);                            \
  mfma32<MHc>(acc, AREG, b);                                \
  __builtin_amdgcn_s_setprio(0);                            \
  if (VM) asm volatile("s_waitcnt vmcnt(6)" ::: "memory");  \
  asm volatile("s_barrier" ::: "memory");

  for (int it = 0; it < nit; ++it) {
    const int t0 = 2 * it;
    const int t1 = t0 + 1;
    const int t2 = (t0 + 2 < nkt) ? t0 + 2 : nkt - 1;
    const int t3 = (t0 + 3 < nkt) ? t0 + 3 : nkt - 1;
    // P1: all buf0 reads (a0 mh0, b, prefetch a1 mh1). Stage A(t1)m1 -> buf1.
    ldA(a0, As[0], wr, 0, lane); ldB4(b, Bs[0], wc, lane);
    ldA(a1, As[0], wr, 1, lane);
    PHASE(0, a0, 0, SAu(1, t1, 1); SAu(1, t1, 3));
    // P2: pure MFMA (a1 prefetched). Stage B(t2)+A(t2)m0 -> buf0 (mh0 rows
    // only -- disjoint from a1's outstanding mh1 reads). vmcnt(6).
    PHASE(1, a1, 1, SB_(0, t2, 0); SB_(0, t2, 1); SAu(0, t2, 0); SAu(0, t2, 2));
    // P3: all buf1 reads. Stage A(t2)m1 -> buf0.
    ldA(a0, As[1], wr, 0, lane); ldB4(b, Bs[1], wc, lane);
    ldA(a1, As[1], wr, 1, lane);
    PHASE(0, a0, 0, SAu(0, t2, 1); SAu(0, t2, 3));
    // P4: pure MFMA. Stage B(t3)+A(t3)m0 -> buf1 (mh0 rows only). vmcnt(6).
    PHASE(1, a1, 1, SB_(1, t3, 0); SB_(1, t3, 1); SAu(1, t3, 0); SAu(1, t3, 2));
  }
#undef PHASE

  const int l15 = lane & 15, g4 = (lane >> 4) * 4;
#pragma unroll
  for (int i = 0; i < 8; ++i) {
#pragma unroll
    for (int j = 0; j < 4; ++j) {
      const int gr = m0 + wr * 128 + i * 16 + g4;
      const int gc = n0 + wc * 64 + j * 16 + l15;
      float bv = OUTF32 ? bias[gc] : 0.0f;
#pragma unroll
      for (int r = 0; r < 4; ++r) {
        float val = acc[i][j][r];
        if (OUTF32) ((float*)Cout)[(size_t)(gr + r) * N + gc] = val + bv;
        else ((u16*)Cout)[(size_t)(gr + r) * N + gc] = f2bf(val);
      }
    }
  }
}

// ---------------- chunked gated attention, 32x32 MFMA, 16 waves -------------
// One block per (b,h,chunk), 1024 threads (4 waves/SIMD — the 32x32 form
// halved LDS traffic, leaving the kernel latency-bound; occupancy now pays).
// Each wave: ONE pass of 32 q. Swapped QK^T, sigma-permuted V columns so the
// lane's C-regs are exactly its PV B-frag (zero cross-lane P traffic).
__global__ __launch_bounds__(1024, 4) void attn_chunk(const u16* __restrict__ qkv,
    const float* __restrict__ lam, u16* __restrict__ aout) {
  __shared__ u16 Ksm[512 * 64];   // [key][dim], slot ^= f(row), f = bits{0,1,3}
  __shared__ u16 Vt[64 * 520];    // [dim][perm(key)], +8 pad per row
  __shared__ float lam_s[512];

  const int tid = threadIdx.x;
  const int lane = tid & 63;
  const int wid = tid >> 6;            // 0..15
  const int blk = blockIdx.x;          // b*128 + h*8 + c
  const int c = blk & 7;
  const int hd = (blk >> 3) & 15;
  const int b = blk >> 7;
  const size_t tok0 = (size_t)b * 4096 + c * 512;
  const u16* qb = qkv + tok0 * 3072 + hd * 64;
  const u16* kb = qb + 1024;
  const u16* vb = qb + 2048;

  if (tid < 512) lam_s[tid] = lam[hd * 4096 + c * 512 + tid];  // incl. 0.125

  // stage K: 16 waves x 8 rows x 4 iters; source col pre-swizzled by f(row)
#pragma unroll
  for (int i = 0; i < 4; ++i) {
    const int r = i * 128 + wid * 8 + (lane >> 3);
    const int f = (r & 3) | (((r >> 3) & 1) << 2);
    gload_lds16(kb + (size_t)r * 3072 + (((lane & 7) ^ f) << 3),
                &Ksm[(i * 128 + wid * 8) * 64]);
  }
  // stage V transposed + column-permuted: key k -> col (k&~31) + (kg&16)
  //   + ((kg>>2)&1)*8 + ((kg&3)|((kg&8)>>1)); pairs (2i,2i+1) stay adjacent.
  {
    const int pr = tid & 255;
    const int k0 = 2 * pr;
    const int kg = k0 & 31;
    const int col = (k0 & ~31) + (kg & 16) + (((kg >> 2) & 1) << 3) +
                    ((kg & 3) | ((kg & 8) >> 1));
    const int db0 = (tid >> 8) * 2;
#pragma unroll
    for (int dbi = 0; dbi < 2; ++dbi) {
      const int d0 = (db0 + dbi) * 8;
      v8s v0 = *(const v8s*)(vb + (size_t)k0 * 3072 + d0);
      v8s v1 = *(const v8s*)(vb + (size_t)(k0 + 1) * 3072 + d0);
#pragma unroll
      for (int j = 0; j < 8; ++j) {
        unsigned pk = (unsigned)(u16)v0[j] | ((unsigned)(u16)v1[j] << 16);
        *(unsigned*)&Vt[(d0 + j) * 520 + col] = pk;
      }
    }
  }
  __syncthreads();

  const int l31 = lane & 31;
  const int hf = lane >> 5;                               // key/dim half
  const int fk = (l31 & 3) | (((l31 >> 3) & 1) << 2);     // f(key row), lane-const

  const int q0 = wid * 32;
  v8s qv[4];
#pragma unroll
  for (int dsec = 0; dsec < 4; ++dsec)
    qv[dsec] = *(const v8s*)(qb + (size_t)(q0 + l31) * 3072 + dsec * 16 + hf * 8);

  float m = -1e30f, sum = 0.0f;
  v16f o0 = {}, o1 = {};

#pragma unroll 1
  for (int kt = 0; kt < 16; ++kt) {
    // S^T tile: 32 keys x 32 q; lane holds q=q0+l31, 16 keys
    v16f acc = {};
#pragma unroll
    for (int dsec = 0; dsec < 4; ++dsec) {
      const v8s kf = *(const v8s*)&Ksm[(kt * 32 + l31) * 64 +
                                       (((dsec * 2 + hf) ^ fk) << 3)];
      acc = __builtin_amdgcn_mfma_f32_32x32x16_bf16(kf, qv[dsec], acc, 0, 0, 0);
    }
    // gate: C reg r -> key kt*32 + (r&3) + 8*(r>>2) + 4*hf
#pragma unroll
    for (int a = 0; a < 4; ++a) {
      const v4f lv = *(const v4f*)&lam_s[kt * 32 + a * 8 + hf * 4];
#pragma unroll
      for (int i = 0; i < 4; ++i) acc[4 * a + i] *= lv[i];
    }
    // defer-max online softmax (T13, THR=8)
    float tm = acc[0];
#pragma unroll
    for (int r = 1; r < 16; ++r) tm = fmaxf(tm, acc[r]);
    tm = fmaxf(tm, __shfl_xor(tm, 32));
    if (!__all(tm <= m + 8.0f)) {
      const float nm = fmaxf(m, tm);
      const float sc = __expf(m - nm);
      sum *= sc;
      o0 *= sc; o1 *= sc;
      m = nm;
    }
    float ps = 0.0f;
#pragma unroll
    for (int r = 0; r < 16; ++r) { acc[r] = __expf(acc[r] - m); ps += acc[r]; }
    sum += ps;
    // PV: B-frags are the lane's own regs in order (sigma-permuted V cols)
    v4u pa, pb;
    pa.x = pk2bf(acc[0], acc[1]);   pa.y = pk2bf(acc[2], acc[3]);
    pa.z = pk2bf(acc[4], acc[5]);   pa.w = pk2bf(acc[6], acc[7]);
    pb.x = pk2bf(acc[8], acc[9]);   pb.y = pk2bf(acc[10], acc[11]);
    pb.z = pk2bf(acc[12], acc[13]); pb.w = pk2bf(acc[14], acc[15]);
    const v8s pfA = __builtin_bit_cast(v8s, pa);
    const v8s pfB = __builtin_bit_cast(v8s, pb);
    const int vcol = kt * 32 + hf * 8;
    const v8s vA0 = *(const v8s*)&Vt[l31 * 520 + vcol];
    const v8s vB0 = *(const v8s*)&Vt[l31 * 520 + vcol + 16];
    const v8s vA1 = *(const v8s*)&Vt[(32 + l31) * 520 + vcol];
    const v8s vB1 = *(const v8s*)&Vt[(32 + l31) * 520 + vcol + 16];
    o0 = __builtin_amdgcn_mfma_f32_32x32x16_bf16(vA0, pfA, o0, 0, 0, 0);
    o0 = __builtin_amdgcn_mfma_f32_32x32x16_bf16(vB0, pfB, o0, 0, 0, 0);
    o1 = __builtin_amdgcn_mfma_f32_32x32x16_bf16(vA1, pfA, o1, 0, 0, 0);
    o1 = __builtin_amdgcn_mfma_f32_32x32x16_bf16(vB1, pfB, o1, 0, 0, 0);
  }

  sum += __shfl_xor(sum, 32);
  const float sv = 1.0f / sum;

  // write O^T: lane's q = l31; dim = dt*32 + 8*a + 4*hf + i
  const size_t obase = (tok0 + q0 + l31) * 1024 + hd * 64;
#pragma unroll
  for (int a = 0; a < 4; ++a) {
    ushort4 w0, w1;
    w0.x = f2bf(o0[4 * a + 0] * sv); w0.y = f2bf(o0[4 * a + 1] * sv);
    w0.z = f2bf(o0[4 * a + 2] * sv); w0.w = f2bf(o0[4 * a + 3] * sv);
    w1.x = f2bf(o1[4 * a + 0] * sv); w1.y = f2bf(o1[4 * a + 1] * sv);
    w1.z = f2bf(o1[4 * a + 2] * sv); w1.w = f2bf(o1[4 * a + 3] * sv);
    *(ushort4*)&aout[obase + 8 * a + 4 * hf] = w0;
    *(ushort4*)&aout[obase + 32 + 8 * a + 4 * hf] = w1;
  }
}

extern "C" void kernel_launch(void* const* d_in, const int* in_sizes, int n_in,
                              void* d_out, int out_size, void* d_ws, size_t ws_size,
                              hipStream_t stream) {
  const float* x    = (const float*)d_in[0];
  const float* Wqkv = (const float*)d_in[1];
  const float* Wout = (const float*)d_in[2];
  const float* bout = (const float*)d_in[3];
  const float* Wl1  = (const float*)d_in[4];
  const float* bl1  = (const float*)d_in[5];
  const float* Wl2  = (const float*)d_in[6];
  const float* bl2  = (const float*)d_in[7];
  float* out = (float*)d_out;

  char* ws = (char*)d_ws;
  u16* xbf    = (u16*)ws; ws += (size_t)16384 * 1024 * 2;
  u16* wqkvbf = (u16*)ws; ws += (size_t)3072 * 1024 * 2;
  u16* woutbf = (u16*)ws; ws += (size_t)1024 * 1024 * 2;
  u16* qkvbf  = (u16*)ws; ws += (size_t)16384 * 3072 * 2;
  u16* aoutbf = (u16*)ws; ws += (size_t)16384 * 1024 * 2;
  float* lam  = (float*)ws; ws += (size_t)16 * 4096 * 4;

  cvt_bf16<<<16384, 256, 0, stream>>>(x, xbf, 16777216 / 4);
  cvt_bf16<<<3072, 256, 0, stream>>>(Wqkv, wqkvbf, 3145728 / 4);
  cvt_bf16<<<1024, 256, 0, stream>>>(Wout, woutbf, 1048576 / 4);
  lam_kernel<<<16, 256, 0, stream>>>(Wl1, bl1, Wl2, bl2, lam);

  // QKV projection: 16384x3072x1024, 768 blocks
  gemm256<0><<<dim3((16384 / 256) * (3072 / 256)), 512, 0, stream>>>(
      xbf, wqkvbf, qkvbf, nullptr, 16384, 3072, 1024);

  attn_chunk<<<512, 1024, 0, stream>>>(qkvbf, lam, aoutbf);

  // output projection: 16384x1024x1024, 256 blocks
  gemm256<1><<<dim3((16384 / 256) * (1024 / 256)), 512, 0, stream>>>(
      aoutbf, woutbf, out, bout, 16384, 1024, 1024);
}